// Round 3
// baseline (8272.936 us; speedup 1.0000x reference)
//
#include <hip/hip_runtime.h>
#include <stdint.h>
#include <stddef.h>
#include <math.h>

// Problem constants
#define B_ 128
#define S_ 1024
#define I_ 512
#define H_ 1024
#define O_ 512

typedef __attribute__((ext_vector_type(4))) float f32x4;
typedef __attribute__((ext_vector_type(8))) short short8;
typedef __attribute__((ext_vector_type(2))) unsigned int uint2v;
typedef __attribute__((ext_vector_type(4))) unsigned int uint4v;

template <bool V> struct BC { static constexpr bool value = V; };

__device__ __forceinline__ unsigned short f2bf(float f) {
    unsigned u = __builtin_bit_cast(unsigned, f);
    u += 0x7fffu + ((u >> 16) & 1u);          // round-to-nearest-even
    return (unsigned short)(u >> 16);
}
__device__ __forceinline__ uint2v pack4(f32x4 v) {
    uint2v r;
    r.x = (unsigned)f2bf(v.x) | ((unsigned)f2bf(v.y) << 16);
    r.y = (unsigned)f2bf(v.z) | ((unsigned)f2bf(v.w) << 16);
    return r;
}
// Agent-scope (sc1) accesses: device-coherent via MALL. Validated (r0/r1).
__device__ __forceinline__ unsigned long long ld_u64_coh(const unsigned long long* p) {
    return __hip_atomic_load(p, __ATOMIC_RELAXED, __HIP_MEMORY_SCOPE_AGENT);
}
__device__ __forceinline__ void st_u32_coh(unsigned int* p, unsigned int v) {
    __hip_atomic_store(p, v, __ATOMIC_RELAXED, __HIP_MEMORY_SCOPE_AGENT);
}
__device__ __forceinline__ unsigned int ld_u32_coh(const unsigned int* p) {
    return __hip_atomic_load(p, __ATOMIC_RELAXED, __HIP_MEMORY_SCOPE_AGENT);
}
__device__ __forceinline__ float fast_tanh(float z) {
    float e = __expf(2.0f * z);
    return 1.0f - 2.0f / (e + 1.0f);
}
// Raw barriers: lgkm-drain only (LDS producer/consumer) — leaves global
// loads in flight across the barrier (unlike __syncthreads' vmcnt(0)).
__device__ __forceinline__ void bar_lgkm() {
    asm volatile("s_waitcnt lgkmcnt(0)\n\ts_barrier" ::: "memory");
    __builtin_amdgcn_sched_barrier(0);
}
__device__ __forceinline__ void bar_only() {
    asm volatile("s_barrier" ::: "memory");
    __builtin_amdgcn_sched_barrier(0);
}

// ---------------- workspace layout (bytes) ----------------
// wfh  : W_hh bf16 frag-major              = 2097152
// wfi  : W_ih bf16 frag-major              = 1048576
// hbuf : [2][8 clusters][16384 els] bf16   =  524288
// cnt  : flags 8x64 u32 | xcc 8x32 u32     =    4096
#define OFF_WFI  2097152UL
#define OFF_HBUF 3145728UL
#define OFF_CNT  3670016UL
#define WS_NEED  (OFF_CNT + 4096UL)

// ---------------- init: zero h0 and sync area ----------------
__global__ void rnn_init(unsigned int* hb32, unsigned int* cnt) {
    int idx = blockIdx.x * 256 + threadIdx.x;     // 65536 threads
    hb32[idx] = 0u;
    hb32[idx + 65536] = 0u;                       // 131072 u32 = 512 KB
    if (blockIdx.x < 4) cnt[blockIdx.x * 256 + threadIdx.x] = 0u;  // 1024 u32
}

// ---------------- W_hh fp32 -> bf16 frag-major ----------------
__global__ void rnn_convw_hh(const float* __restrict__ Whh,
                             unsigned short* __restrict__ wfh) {
    int G = blockIdx.x * 256 + threadIdx.x;       // 0..131071
    int l = G & 63, rest = G >> 6;
    int kc = rest & 31, t = (rest >> 5) & 1, wgn = rest >> 6;
    int n  = wgn * 32 + t * 16 + (l & 15);
    int k0 = kc * 32 + (l >> 4) * 8;
    const float* src = Whh + (size_t)n * H_ + k0;
    f32x4 f0 = *(const f32x4*)src, f1 = *(const f32x4*)(src + 4);
    uint2v a = pack4(f0), b = pack4(f1);
    uint4v pk; pk.x = a.x; pk.y = a.y; pk.z = b.x; pk.w = b.y;
    *(uint4v*)(wfh + (size_t)G * 8) = pk;
}

// ---------------- W_ih fp32 -> bf16 frag-major ----------------
__global__ void rnn_convw_ih(const float* __restrict__ Wih,
                             unsigned short* __restrict__ wfi) {
    int G = blockIdx.x * 256 + threadIdx.x;       // 0..65535
    int l = G & 63, rest = G >> 6;
    int kc2 = rest & 15, t = (rest >> 4) & 1, wgn = rest >> 5;
    int n  = wgn * 32 + t * 16 + (l & 15);
    int k0 = kc2 * 32 + (l >> 4) * 8;
    const float* src = Wih + (size_t)n * I_ + k0;
    f32x4 f0 = *(const f32x4*)src, f1 = *(const f32x4*)(src + 4);
    uint2v a = pack4(f0), b = pack4(f1);
    uint4v pk; pk.x = a.x; pk.y = a.y; pk.z = b.x; pk.w = b.y;
    *(uint4v*)(wfi + (size_t)G * 8) = pk;
}

// ---------------- persistent fused recurrence ----------------
// 8 clusters x 32 WGs. Weights in registers; h double-buffered in global.
// FAST (cluster XCD-uniform, verified at runtime): exchange via XCD L2.
//   - consumer loads use `nt` (no-L1-allocate): h/flag lines are NEVER
//     L1-resident (stores are write-through no-allocate, readbacks nt),
//     so every read is serviced by the coherent L2. No stale-L1 hazard.
//   - producer proves L2 commit by value-verified nt readback before
//     raising its flag (no reliance on store-ack semantics).
// FALLBACK: sc1/MALL exchange (validated rounds 0-1), same structure,
// identical arithmetic (placement flips cannot change output bits).
__global__ __launch_bounds__(256, 1) void rnn_rec(
    const float* __restrict__ x,
    const unsigned short* __restrict__ wfh,
    const unsigned short* __restrict__ wfi,
    const float* __restrict__ bih, const float* __restrict__ bhh,
    unsigned short* __restrict__ hbuf,
    unsigned int* __restrict__ cnt)
{
    __shared__ unsigned short ldsX[8192];    // 16 KB x stage (frag-major)
    __shared__ f32x4 redv[512];              //  8 KB 4-partial reduce
    __shared__ int fastmode;

    int g = blockIdx.x & 7, wgn = blockIdx.x >> 3;
    int tid = threadIdx.x, l = tid & 63, w = tid >> 6;
    int li = l & 15, q = l >> 4;

    // B-fragments resident: wave w -> K-quarter w, both n-tiles
    short8 wh[2][8], wi[2][4];
    #pragma unroll
    for (int t2 = 0; t2 < 2; ++t2) {
        #pragma unroll
        for (int c = 0; c < 8; ++c)
            wh[t2][c] = *(const short8*)(wfh +
                ((size_t)((wgn * 2 + t2) * 32 + w * 8 + c)) * 512 + l * 8);
        #pragma unroll
        for (int c = 0; c < 4; ++c)
            wi[t2][c] = *(const short8*)(wfi +
                ((size_t)((wgn * 2 + t2) * 16 + w * 4 + c)) * 512 + l * 8);
    }

    int hcol = wgn * 32 + w * 16 + li;       // finalize col (waves 0,1)
    float bias = 0.f;
    if (w < 2) bias = bih[hcol] + bhh[hcol];
    int q2 = (hcol >> 3) & 3, j2 = hcol & 7;
    unsigned int* flg = cnt + g * 64;        // cluster's private flag lines

    // ---- XCD-uniformity consensus (agent-scope, one round) ----
    unsigned xcc = 0;
    asm volatile("s_getreg_b32 %0, hwreg(HW_REG_XCC_ID)" : "=s"(xcc));
    unsigned int* xa = cnt + 512 + g * 64;
    if (tid == 0) st_u32_coh(xa + wgn, xcc + 1u);
    if (tid < 64) {
        unsigned v = 0; int polls = 0, dead = 0;
        while (true) {
            v = ld_u32_coh(xa + (l & 31));
            if (__ballot((int)(v != 0u)) == ~0ull) break;
            __builtin_amdgcn_s_sleep(1);
            if (++polls > (1 << 22)) { dead = 1; break; }
        }
        int uni = (!dead && __ballot((int)(v == xcc + 1u)) == ~0ull) ? 1 : 0;
        if (tid == 0) fastmode = uni;
    }

    // prologue: x(s=0) into registers (packed at loop top)
    f32x4 xr[8];
    #pragma unroll
    for (int i = 0; i < 4; ++i) {
        int G = tid + i * 256, l2 = G & 63, kc2 = G >> 6;
        const float* src = x + ((size_t)(g * 16 + (l2 & 15)) * S_ + 0) * I_
                             + kc2 * 32 + (l2 >> 4) * 8;
        xr[2 * i]     = *(const f32x4*)src;
        xr[2 * i + 1] = *(const f32x4*)(src + 4);
    }
    __syncthreads();                         // fastmode visible
    const bool fast = (fastmode != 0);

    auto body = [&](auto fc) {
        constexpr bool FAST = decltype(fc)::value;
        int bail = 0;
        #pragma unroll 1
        for (int s = 0; s < S_; ++s) {
            int cur = s & 1, nxt = cur ^ 1;
            int havex = (s + 1 < S_);
            int sp = (s + 1) & (S_ - 1);     // wrap on last iter (loads only)

            // ---- pack ldsX from xr (consumes previous x loads) ----
            #pragma unroll
            for (int i = 0; i < 4; ++i) {
                int G = tid + i * 256;
                uint2v a = pack4(xr[2 * i]), b2 = pack4(xr[2 * i + 1]);
                uint4v pk; pk.x = a.x; pk.y = a.y; pk.z = b2.x; pk.w = b2.y;
                *(uint4v*)&ldsX[(size_t)G * 8] = pk;
            }

            // ---- issue h loads (8 frags x 16B per lane, K-quarter w) ----
            uint4v hv[8];
            unsigned long long h64a[8], h64b[8];
            const char* hb = (const char*)hbuf + (size_t)cur * 262144
                + (size_t)g * 32768 + (size_t)w * 8192 + (size_t)l * 16;
            if constexpr (FAST) {
                #pragma unroll
                for (int c = 0; c < 8; ++c) {
                    const char* pc = hb + c * 1024;
                    asm volatile("global_load_dwordx4 %0, %1, off sc0 nt"
                                 : "=&v"(hv[c]) : "v"(pc) : "memory");
                }
                __builtin_amdgcn_sched_barrier(0);
            } else {
                #pragma unroll
                for (int c = 0; c < 8; ++c) {
                    h64a[c] = ld_u64_coh((const unsigned long long*)(hb + c * 1024));
                    h64b[c] = ld_u64_coh((const unsigned long long*)(hb + c * 1024 + 8));
                }
            }

            bar_lgkm();                      // (P) ldsX ready; h stays in flight

            // ---- x-projection MFMAs (under h-load shadow) ----
            f32x4 a0 = {0.f, 0.f, 0.f, 0.f}, a1 = {0.f, 0.f, 0.f, 0.f};
            #pragma unroll
            for (int c = 0; c < 4; ++c) {
                short8 a = *(const short8*)&ldsX[(w * 4 + c) * 512 + l * 8];
                a0 = __builtin_amdgcn_mfma_f32_16x16x32_bf16(a, wi[0][c], a0, 0, 0, 0);
                a1 = __builtin_amdgcn_mfma_f32_16x16x32_bf16(a, wi[1][c], a1, 0, 0, 0);
            }

            if constexpr (FAST) {
                // only the 8 h loads are outstanding here (x for s+1 not
                // yet issued) — absolute wait, no counted vmcnt.
                asm volatile("s_waitcnt vmcnt(0)" ::: "memory");
                __builtin_amdgcn_sched_barrier(0);   // rule #18 fence
            }
            // ---- h MFMAs ----
            #pragma unroll
            for (int c = 0; c < 8; ++c) {
                short8 af;
                if constexpr (FAST) {
                    af = __builtin_bit_cast(short8, hv[c]);
                } else {
                    union { unsigned long long qw[2]; short8 v; } uu;
                    uu.qw[0] = h64a[c]; uu.qw[1] = h64b[c];
                    af = uu.v;
                }
                a0 = __builtin_amdgcn_mfma_f32_16x16x32_bf16(af, wh[0][c], a0, 0, 0, 0);
                a1 = __builtin_amdgcn_mfma_f32_16x16x32_bf16(af, wh[1][c], a1, 0, 0, 0);
            }

            // ---- issue x loads for s+1 (in flight until next pack) ----
            #pragma unroll
            for (int i = 0; i < 4; ++i) {
                int G = tid + i * 256, l2 = G & 63, kc2 = G >> 6;
                const float* src = x + ((size_t)(g * 16 + (l2 & 15)) * S_ + sp) * I_
                                     + kc2 * 32 + (l2 >> 4) * 8;
                xr[2 * i]     = *(const f32x4*)src;
                xr[2 * i + 1] = *(const f32x4*)(src + 4);
            }

            redv[(w * 2 + 0) * 64 + l] = a0;
            redv[(w * 2 + 1) * 64 + l] = a1;
            bar_lgkm();                      // (B) partials ready

            if (w < 2) {                     // finalize n-tile t=w
                f32x4 p0 = redv[(0 * 2 + w) * 64 + l];
                f32x4 p1 = redv[(1 * 2 + w) * 64 + l];
                f32x4 p2 = redv[(2 * 2 + w) * 64 + l];
                f32x4 p3 = redv[(3 * 2 + w) * 64 + l];
                unsigned int* hout32 = (unsigned int*)(hbuf
                    + (size_t)nxt * 131072 + (size_t)g * 16384
                    + (size_t)wgn * 512 + j2);
                unsigned wv0 = 0, wv1 = 0, wv2 = 0, wv3 = 0;
                unsigned int *dp0 = 0, *dp1 = 0, *dp2 = 0, *dp3 = 0;
                #pragma unroll
                for (int i = 0; i < 4; ++i) {
                    float z = p0[i] + p1[i] + p2[i] + p3[i] + bias;
                    float v = fast_tanh(z);
                    unsigned short mybf = f2bf(v);
                    unsigned nb = (unsigned)__shfl_xor((int)mybf, 1, 64) & 0xffffu;
                    unsigned word = (unsigned)mybf | (nb << 16);
                    unsigned int* dst = hout32 + (q2 * 16 + q * 4 + i) * 4;
                    if ((li & 1) == 0) {
                        if constexpr (FAST) *(volatile unsigned int*)dst = word;
                        else st_u32_coh(dst, word);
                    }
                    if (i == 0) { wv0 = word; dp0 = dst; }
                    else if (i == 1) { wv1 = word; dp1 = dst; }
                    else if (i == 2) { wv2 = word; dp2 = dst; }
                    else { wv3 = word; dp3 = dst; }
                }
                if constexpr (FAST) {
                    // value-verified readback: proves L2 commit before flag
                    if ((li & 1) == 0) {
                        int tries = 0;
                        while (true) {
                            unsigned g0, g1, g2, g3;
                            asm volatile(
                                "global_load_dword %0, %4, off sc0 nt\n\t"
                                "global_load_dword %1, %5, off sc0 nt\n\t"
                                "global_load_dword %2, %6, off sc0 nt\n\t"
                                "global_load_dword %3, %7, off sc0 nt\n\t"
                                "s_waitcnt vmcnt(0)"
                                : "=&v"(g0), "=&v"(g1), "=&v"(g2), "=&v"(g3)
                                : "v"(dp0), "v"(dp1), "v"(dp2), "v"(dp3)
                                : "memory");
                            if (g0 == wv0 && g1 == wv1 && g2 == wv2 && g3 == wv3) break;
                            if (++tries > (1 << 20)) break;
                        }
                    }
                    __builtin_amdgcn_sched_barrier(0);
                } else {
                    asm volatile("s_waitcnt vmcnt(0)" ::: "memory");  // sc1 drain
                    __builtin_amdgcn_sched_barrier(0);
                }
                // dual flags: wave w raises slot w*32+wgn
                if (l == 0) {
                    if constexpr (FAST)
                        *(volatile unsigned int*)(flg + w * 32 + wgn) = (unsigned)(s + 1);
                    else
                        st_u32_coh(flg + w * 32 + wgn, (unsigned)(s + 1));
                }
            }

            if (havex) {
                // wave 0: one coalesced poll of all 64 flag slots + ballot
                if (w == 0 && !bail) {
                    unsigned target = (unsigned)(s + 1);
                    int polls = 0;
                    while (true) {
                        unsigned v2;
                        if constexpr (FAST) {
                            asm volatile(
                                "global_load_dword %0, %1, off sc0 nt\n\t"
                                "s_waitcnt vmcnt(0)"
                                : "=&v"(v2) : "v"(flg + l) : "memory");
                        } else {
                            v2 = ld_u32_coh(flg + l);
                        }
                        if (__ballot((int)(v2 >= target)) == ~0ull) break;
                        __builtin_amdgcn_s_sleep(1);
                        if (++polls > (1 << 22)) { bail = 1; break; }  // anti-hang
                    }
                }
                bar_only();                  // (D) step barrier passed
            }
        }
    };
    if (fast) body(BC<true>{});
    else      body(BC<false>{});
}

// ---------------- out = hT @ W_fc^T + b_fc ----------------
__global__ __launch_bounds__(256) void rnn_fc(
    const unsigned short* __restrict__ hb0,
    const float* __restrict__ Wfc, const float* __restrict__ bfc,
    float* __restrict__ out)
{
    __shared__ unsigned short ldsB[8 * 64 * 8];   // 8 KB
    int n_blk = blockIdx.x;                       // 4 blocks of 128 o-cols
    int tid = threadIdx.x, l = tid & 63, w = tid >> 6;
    int li = l & 15, q = l >> 4;
    f32x4 acc[8][2];
    f32x4 z = {0.f, 0.f, 0.f, 0.f};
    #pragma unroll
    for (int mb = 0; mb < 8; ++mb) { acc[mb][0] = z; acc[mb][1] = z; }

    for (int kc = 0; kc < 32; ++kc) {
        #pragma unroll
        for (int u = 0; u < 2; ++u) {
            int G = tid * 2 + u;
            int nt = G >> 6, ll = G & 63;
            int n = n_blk * 128 + nt * 16 + (ll & 15);
            int k = kc * 32 + (ll >> 4) * 8;
            const float* src = Wfc + (size_t)n * H_ + k;
            f32x4 f0 = *(const f32x4*)src, f1 = *(const f32x4*)(src + 4);
            uint2v a = pack4(f0), b = pack4(f1);
            uint4v pk; pk.x = a.x; pk.y = a.y; pk.z = b.x; pk.w = b.y;
            *(uint4v*)&ldsB[G * 8] = pk;
        }
        __syncthreads();
        short8 bfr[2];
        #pragma unroll
        for (int tn = 0; tn < 2; ++tn)
            bfr[tn] = *(const short8*)&ldsB[((w * 2 + tn) * 64 + l) * 8];
        #pragma unroll
        for (int mb = 0; mb < 8; ++mb) {
            short8 a = *(const short8*)(hb0 + (size_t)mb * 16384 + kc * 512 + l * 8);
            acc[mb][0] = __builtin_amdgcn_mfma_f32_16x16x32_bf16(a, bfr[0], acc[mb][0], 0, 0, 0);
            acc[mb][1] = __builtin_amdgcn_mfma_f32_16x16x32_bf16(a, bfr[1], acc[mb][1], 0, 0, 0);
        }
        __syncthreads();
    }
    #pragma unroll
    for (int mb = 0; mb < 8; ++mb)
        #pragma unroll
        for (int tn = 0; tn < 2; ++tn)
            #pragma unroll
            for (int i = 0; i < 4; ++i) {
                int b = mb * 16 + q * 4 + i;
                int o = n_blk * 128 + (w * 2 + tn) * 16 + li;
                out[(size_t)b * O_ + o] = acc[mb][tn][i] + bfc[o];
            }
}

extern "C" void kernel_launch(void* const* d_in, const int* in_sizes, int n_in,
                              void* d_out, int out_size, void* d_ws, size_t ws_size,
                              hipStream_t stream) {
    const float* x   = (const float*)d_in[0];
    const float* Wih = (const float*)d_in[1];
    const float* Whh = (const float*)d_in[2];
    const float* bih = (const float*)d_in[3];
    const float* bhh = (const float*)d_in[4];
    const float* Wfc = (const float*)d_in[5];
    const float* bfc = (const float*)d_in[6];
    float* out = (float*)d_out;
    (void)in_sizes; (void)n_in; (void)out_size;

    if (ws_size < WS_NEED) return;   // fail visibly (absmax), never fault

    char* ws = (char*)d_ws;
    unsigned short* wfh  = (unsigned short*)ws;
    unsigned short* wfi  = (unsigned short*)(ws + OFF_WFI);
    unsigned short* hbuf = (unsigned short*)(ws + OFF_HBUF);
    unsigned int*   cnt  = (unsigned int*)(ws + OFF_CNT);

    rnn_init<<<256, 256, 0, stream>>>((unsigned int*)hbuf, cnt);
    rnn_convw_hh<<<512, 256, 0, stream>>>(Whh, wfh);
    rnn_convw_ih<<<256, 256, 0, stream>>>(Wih, wfi);

    const float* xa = x; const float* biha = bih; const float* bhha = bhh;
    void* args[] = {(void*)&xa, (void*)&wfh, (void*)&wfi,
                    (void*)&biha, (void*)&bhha, (void*)&hbuf, (void*)&cnt};
    hipLaunchCooperativeKernel((const void*)rnn_rec, dim3(256), dim3(256),
                               args, 0, stream);

    rnn_fc<<<4, 256, 0, stream>>>(hbuf, Wfc, bfc, out);
}